// Round 6
// baseline (206.166 us; speedup 1.0000x reference)
//
#include <hip/hip_runtime.h>

#define BB 32
#define CC 128
#define HH 128
#define WW 128
#define HWSZ (HH * WW)          // 16384
#define CHW (CC * HWSZ)         // 2097152
#define S4 (HWSZ / 4)           // 4096
#define RPB 2                   // output rows per block
#define HALO 8                  // RPB + 6
#define NBAND (HH / RPB)        // 64

typedef float vfloat4 __attribute__((ext_vector_type(4)));

__device__ __forceinline__ vfloat4 fmax4(vfloat4 a, vfloat4 b) {
    vfloat4 r;
    r.x = fmaxf(a.x, b.x);
    r.y = fmaxf(a.y, b.y);
    r.z = fmaxf(a.z, b.z);
    r.w = fmaxf(a.w, b.w);
    return r;
}

// One block = (batch b, 2-row band). 2048 blocks, 8/CU.
__global__ __launch_bounds__(256, 4) void sa_onepass(
    const float* __restrict__ x, const float* __restrict__ cw,
    float* __restrict__ out) {
    __shared__ float m_lds[2][HALO][WW];   // 8 KiB
    __shared__ float sig_lds[RPB][WW];     // 1 KiB
    __shared__ float wsh[2 * 49];

    const int tid = threadIdx.x;
    // XCD swizzle: same XCD gets contiguous bands of the same batch.
    const int wg  = blockIdx.x;            // 0..2047
    const int xcd = wg & 7;
    const int lin = wg >> 3;               // 0..255
    const int b   = xcd * 4 + (lin >> 6);  // 0..31
    const int hb  = lin & 63;              // 0..63
    const int h0  = hb * RPB;

    if (tid < 98) wsh[tid] = cw[tid];

    const float* xb = x + (size_t)b * CHW;

    // ---------- Phase 1: channel reduce halo rows h0-3 .. h0+4 ----------
    // thread (r = tid>>5 in 0..7, w4 = tid&31): exactly one row, 128 channels.
    {
        const int r  = tid >> 5;
        const int w4 = tid & 31;
        const int gh = h0 - 3 + r;
        const bool ok = (gh >= 0) && (gh < HH);
        vfloat4 sum = {0.f, 0.f, 0.f, 0.f}, mx = sum;
        if (ok) {
            const vfloat4* p = (const vfloat4*)(xb + gh * WW) + w4;
            vfloat4 v = p[0];
            sum = v; mx = v;
            #pragma unroll 8
            for (int c = 1; c < CC; ++c) {
                vfloat4 t = p[(size_t)c * S4];
                sum += t;
                mx = fmax4(mx, t);
            }
        }
        const float invC = 1.0f / (float)CC;
        vfloat4 avg = sum * invC;
        *(vfloat4*)&m_lds[0][r][w4 * 4] = avg;
        *(vfloat4*)&m_lds[1][r][w4 * 4] = mx;
    }
    __syncthreads();

    // ---------- Phase 2: 7x7 conv + sigmoid, one scalar output/thread ----
    // thread -> (hr = tid>>7 in 0..1, w = tid&127). Stride-1 LDS reads.
    {
        const int hr = tid >> 7;
        const int w  = tid & 127;
        float attn = 0.f;
        #pragma unroll
        for (int ic = 0; ic < 2; ++ic) {
            #pragma unroll
            for (int kh = 0; kh < 7; ++kh) {
                const float* row = &m_lds[ic][hr + kh][0];
                #pragma unroll
                for (int kw = 0; kw < 7; ++kw) {
                    int wi = w - 3 + kw;
                    float v = (wi >= 0 && wi < WW) ? row[wi] : 0.0f;
                    attn = fmaf(v, wsh[ic * 49 + kh * 7 + kw], attn);
                }
            }
        }
        sig_lds[hr][w] = 1.0f / (1.0f + __expf(-attn));
    }
    __syncthreads();

    // ---------- Phase 3: out = x * sig, channels split 4-way ------------
    // thread -> (cg = tid>>6, pos = tid&63 -> hr = pos>>5, w4 = pos&31)
    {
        const int cg = tid >> 6;           // 0..3
        const int pos = tid & 63;
        const int hr = pos >> 5;
        const int w4 = pos & 31;
        vfloat4 sig = *(const vfloat4*)&sig_lds[hr][w4 * 4];
        const int s = (h0 + hr) * WW + w4 * 4;
        const vfloat4* px = (const vfloat4*)xb + (s >> 2);
        vfloat4* po = (vfloat4*)(out + (size_t)b * CHW) + (s >> 2);
        #pragma unroll 4
        for (int c = cg * 32; c < cg * 32 + 32; ++c) {
            vfloat4 v = px[(size_t)c * S4];
            v *= sig;
            __builtin_nontemporal_store(v, po + (size_t)c * S4);
        }
    }
}

extern "C" void kernel_launch(void* const* d_in, const int* in_sizes, int n_in,
                              void* d_out, int out_size, void* d_ws, size_t ws_size,
                              hipStream_t stream) {
    const float* x  = (const float*)d_in[0];
    const float* cw = (const float*)d_in[1];
    float* out = (float*)d_out;

    sa_onepass<<<BB * NBAND, 256, 0, stream>>>(x, cw, out);  // 2048 blocks
}

// Round 7
// 174.740 us; speedup vs baseline: 1.1798x; 1.1798x over previous
//
#include <hip/hip_runtime.h>

#define BB 32
#define CC 128
#define HH 128
#define WW 128
#define HWSZ (HH * WW)          // 16384
#define CHW (CC * HWSZ)         // 2097152
#define S4 (HWSZ / 4)           // 4096
#define RPB 8                   // output rows per block
#define HALO 14                 // RPB + 6 (conv radius 3 each side)

typedef float vfloat4 __attribute__((ext_vector_type(4)));

__device__ __forceinline__ vfloat4 fmax4(vfloat4 a, vfloat4 b) {
    vfloat4 r;
    r.x = fmaxf(a.x, b.x);
    r.y = fmaxf(a.y, b.y);
    r.z = fmaxf(a.z, b.z);
    r.w = fmaxf(a.w, b.w);
    return r;
}

// One block = (batch b, 8-row band). Three phases, no global intermediates.
__global__ __launch_bounds__(256, 2) void sa_onepass(
    const float* __restrict__ x, const float* __restrict__ cw,
    float* __restrict__ out) {
    __shared__ float m_lds[2][HALO][WW];   // [avg/max][halo row][w] = 14 KiB
    __shared__ float wsh[2 * 49];

    const int tid = threadIdx.x;
    // XCD swizzle: adjacent h-bands of the same batch land on the same XCD
    // (round-robin dispatch: blockIdx % 8 = XCD), so halo reads hit L2.
    const int wg  = blockIdx.x;            // 0..511
    const int xcd = wg & 7;
    const int lin = wg >> 3;               // 0..63
    const int b   = xcd * 4 + (lin >> 4);  // 0..31
    const int hb  = lin & 15;              // 0..15
    const int h0  = hb * RPB;

    if (tid < 98) wsh[tid] = cw[tid];

    const int r0 = tid >> 5;               // 0..7  (halo row A; own row index)
    const int w4 = tid & 31;               // float4 column 0..31
    const float* xb = x + (size_t)b * CHW;

    // ---------- Phase 1: channel reduce rows h0-3 .. h0+10 ----------
    // Thread A-position: halo row r0; B-position: halo row r0+8 (waves 0-2 only).
    const bool actB = (r0 < HALO - 8);     // r0 < 6  -> wave-uniform
    const int gh_a = h0 - 3 + r0;
    const int gh_b = h0 - 3 + r0 + 8;
    const bool okA = (gh_a >= 0) && (gh_a < HH);
    const bool okB = actB && (gh_b < HH);  // gh_b >= 5 always
    const int cha = gh_a < 0 ? 0 : (gh_a > HH - 1 ? HH - 1 : gh_a);
    const int chb = gh_b > HH - 1 ? HH - 1 : gh_b;

    const vfloat4* pA = (const vfloat4*)(xb + cha * WW) + w4;
    const vfloat4* pB = (const vfloat4*)(xb + chb * WW) + w4;

    vfloat4 sumA, mxA;
    {
        vfloat4 v = pA[0];
        sumA = v; mxA = v;
    }
    #pragma unroll 4
    for (int c = 1; c < CC; ++c) {
        vfloat4 v = pA[(size_t)c * S4];
        sumA += v;
        mxA = fmax4(mxA, v);
    }
    vfloat4 sumB = {0.f, 0.f, 0.f, 0.f}, mxB = sumB;
    if (actB) {                             // whole wave 3 skips: no divergence
        vfloat4 v = pB[0];
        sumB = v; mxB = v;
        #pragma unroll 4
        for (int c = 1; c < CC; ++c) {
            vfloat4 t = pB[(size_t)c * S4];
            sumB += t;
            mxB = fmax4(mxB, t);
        }
    }

    const float invC = 1.0f / (float)CC;
    {
        vfloat4 avgA = sumA * invC;
        if (!okA) { avgA = (vfloat4){0,0,0,0}; mxA = (vfloat4){0,0,0,0}; }
        *(vfloat4*)&m_lds[0][r0][w4 * 4] = avgA;
        *(vfloat4*)&m_lds[1][r0][w4 * 4] = mxA;
        if (actB) {
            vfloat4 avgB = sumB * invC;
            if (!okB) { avgB = (vfloat4){0,0,0,0}; mxB = (vfloat4){0,0,0,0}; }
            *(vfloat4*)&m_lds[0][r0 + 8][w4 * 4] = avgB;
            *(vfloat4*)&m_lds[1][r0 + 8][w4 * 4] = mxB;
        }
    }
    __syncthreads();

    // ---------- Phase 2: 7x7 conv + sigmoid (all from LDS) ----------
    const int hr = r0;                      // own row within band
    const int w0 = w4 * 4;
    float attn[4] = {0.f, 0.f, 0.f, 0.f};
    #pragma unroll
    for (int ic = 0; ic < 2; ++ic) {
        #pragma unroll
        for (int kh = 0; kh < 7; ++kh) {
            // global input row = h0 + hr + kh - 3  <->  halo row hr + kh
            const float* row = &m_lds[ic][hr + kh][0];
            float seg[10];
            #pragma unroll
            for (int k = 0; k < 10; ++k) {
                int wi = w0 - 3 + k;
                seg[k] = (wi >= 0 && wi < WW) ? row[wi] : 0.0f;
            }
            #pragma unroll
            for (int kw = 0; kw < 7; ++kw) {
                float wgt = wsh[ic * 49 + kh * 7 + kw];
                attn[0] = fmaf(seg[kw + 0], wgt, attn[0]);
                attn[1] = fmaf(seg[kw + 1], wgt, attn[1]);
                attn[2] = fmaf(seg[kw + 2], wgt, attn[2]);
                attn[3] = fmaf(seg[kw + 3], wgt, attn[3]);
            }
        }
    }
    vfloat4 sig;
    sig.x = 1.0f / (1.0f + __expf(-attn[0]));
    sig.y = 1.0f / (1.0f + __expf(-attn[1]));
    sig.z = 1.0f / (1.0f + __expf(-attn[2]));
    sig.w = 1.0f / (1.0f + __expf(-attn[3]));

    // ---------- Phase 3: out = x * sig for own row, reversed c (LRU-friendly) --
    // Single-variable experiment vs R5: PLAIN stores (no nontemporal) so writes
    // batch in L2 and evict in bursts instead of interleaving with reads at HBM.
    const int s = (h0 + hr) * WW + w0;
    const vfloat4* px = (const vfloat4*)xb + (s >> 2);
    vfloat4* po = (vfloat4*)(out + (size_t)b * CHW) + (s >> 2);
    #pragma unroll 4
    for (int c = CC - 1; c >= 0; --c) {
        vfloat4 v = px[(size_t)c * S4];
        v *= sig;
        po[(size_t)c * S4] = v;
    }
}

extern "C" void kernel_launch(void* const* d_in, const int* in_sizes, int n_in,
                              void* d_out, int out_size, void* d_ws, size_t ws_size,
                              hipStream_t stream) {
    const float* x  = (const float*)d_in[0];
    const float* cw = (const float*)d_in[1];
    float* out = (float*)d_out;

    sa_onepass<<<BB * (HH / RPB), 256, 0, stream>>>(x, cw, out);  // 512 blocks
}

// Round 8
// 141.050 us; speedup vs baseline: 1.4616x; 1.2388x over previous
//
#include <hip/hip_runtime.h>

#define BB 32
#define CC 128
#define HH 128
#define WW 128
#define HWSZ (HH * WW)          // 16384
#define CHW (CC * HWSZ)         // 2097152
#define S4 (HWSZ / 4)           // 4096
#define RPB 8                   // output rows per block
#define HALO 14                 // RPB + 6 (conv radius 3 each side)

typedef float vfloat4 __attribute__((ext_vector_type(4)));

__device__ __forceinline__ vfloat4 fmax4(vfloat4 a, vfloat4 b) {
    vfloat4 r;
    r.x = fmaxf(a.x, b.x);
    r.y = fmaxf(a.y, b.y);
    r.z = fmaxf(a.z, b.z);
    r.w = fmaxf(a.w, b.w);
    return r;
}

// One block = (batch b, 8-row band). Three phases, no global intermediates.
__global__ __launch_bounds__(256, 2) void sa_onepass(
    const float* __restrict__ x, const float* __restrict__ cw,
    float* __restrict__ out) {
    __shared__ float m_lds[2][HALO][WW];   // 14 KiB
    __shared__ float sig_lds[RPB][WW];     // 4 KiB
    __shared__ float wsh[2 * 49];

    const int tid = threadIdx.x;
    // XCD swizzle: adjacent h-bands of the same batch land on the same XCD.
    const int wg  = blockIdx.x;            // 0..511
    const int xcd = wg & 7;
    const int lin = wg >> 3;               // 0..63
    const int b   = xcd * 4 + (lin >> 4);  // 0..31
    const int hb  = lin & 15;              // 0..15
    const int h0  = hb * RPB;

    if (tid < 98) wsh[tid] = cw[tid];

    const int r0 = tid >> 5;               // 0..7
    const int w4 = tid & 31;               // float4 column 0..31
    const float* xb = x + (size_t)b * CHW;

    // ---------- Phase 1: channel reduce rows h0-3 .. h0+10 ----------
    const bool actB = (r0 < HALO - 8);     // r0 < 6 -> wave-uniform
    const int gh_a = h0 - 3 + r0;
    const int gh_b = h0 - 3 + r0 + 8;
    const bool okA = (gh_a >= 0) && (gh_a < HH);
    const bool okB = actB && (gh_b < HH);
    const int cha = gh_a < 0 ? 0 : (gh_a > HH - 1 ? HH - 1 : gh_a);
    const int chb = gh_b > HH - 1 ? HH - 1 : gh_b;

    const vfloat4* pA = (const vfloat4*)(xb + cha * WW) + w4;
    const vfloat4* pB = (const vfloat4*)(xb + chb * WW) + w4;

    vfloat4 sumA, mxA;
    {
        vfloat4 v = pA[0];
        sumA = v; mxA = v;
    }
    #pragma unroll 8
    for (int c = 1; c < CC; ++c) {
        vfloat4 v = pA[(size_t)c * S4];
        sumA += v;
        mxA = fmax4(mxA, v);
    }
    vfloat4 sumB = {0.f, 0.f, 0.f, 0.f}, mxB = sumB;
    if (actB) {                             // whole wave 3 skips
        vfloat4 v = pB[0];
        sumB = v; mxB = v;
        #pragma unroll 8
        for (int c = 1; c < CC; ++c) {
            vfloat4 t = pB[(size_t)c * S4];
            sumB += t;
            mxB = fmax4(mxB, t);
        }
    }

    const float invC = 1.0f / (float)CC;
    {
        vfloat4 avgA = sumA * invC;
        if (!okA) { avgA = (vfloat4){0,0,0,0}; mxA = (vfloat4){0,0,0,0}; }
        *(vfloat4*)&m_lds[0][r0][w4 * 4] = avgA;
        *(vfloat4*)&m_lds[1][r0][w4 * 4] = mxA;
        if (actB) {
            vfloat4 avgB = sumB * invC;
            if (!okB) { avgB = (vfloat4){0,0,0,0}; mxB = (vfloat4){0,0,0,0}; }
            *(vfloat4*)&m_lds[0][r0 + 8][w4 * 4] = avgB;
            *(vfloat4*)&m_lds[1][r0 + 8][w4 * 4] = mxB;
        }
    }
    __syncthreads();

    // ---------- Phase 2: conv 7x7 + sigmoid, conflict-free LDS ----------
    // thread -> (q = tid>>7: row group of 4, w = tid&127: one column).
    // All LDS reads are stride-1 across lanes (R6 pattern: 0 conflicts).
    {
        const int q = tid >> 7;            // 0..1 -> rows q*4 .. q*4+3
        const int w = tid & 127;
        float attn[4] = {0.f, 0.f, 0.f, 0.f};
        #pragma unroll
        for (int ic = 0; ic < 2; ++ic) {
            #pragma unroll
            for (int L = 0; L < 10; ++L) { // LDS row = q*4 + L
                const float* row = &m_lds[ic][q * 4 + L][0];
                #pragma unroll
                for (int kw = 0; kw < 7; ++kw) {
                    int wi = w - 3 + kw;
                    float v = (wi >= 0 && wi < WW) ? row[wi] : 0.0f;
                    #pragma unroll
                    for (int j = 0; j < 4; ++j) {
                        const int kh = L - j;          // compile-time after unroll
                        if (kh >= 0 && kh <= 6)
                            attn[j] = fmaf(v, wsh[ic * 49 + kh * 7 + kw], attn[j]);
                    }
                }
            }
        }
        #pragma unroll
        for (int j = 0; j < 4; ++j)
            sig_lds[q * 4 + j][w] = 1.0f / (1.0f + __expf(-attn[j]));
    }
    __syncthreads();

    // ---------- Phase 3: out = x * sig, 8-channel batches, reversed ----
    {
        vfloat4 sig = *(const vfloat4*)&sig_lds[r0][w4 * 4];
        const int s = (h0 + r0) * WW + w4 * 4;
        const vfloat4* px = (const vfloat4*)xb + (s >> 2);
        vfloat4* po = (vfloat4*)(out + (size_t)b * CHW) + (s >> 2);
        #pragma unroll 1
        for (int c0 = CC - 8; c0 >= 0; c0 -= 8) {
            vfloat4 v[8];
            #pragma unroll
            for (int j = 0; j < 8; ++j)
                v[j] = px[(size_t)(c0 + 7 - j) * S4];
            #pragma unroll
            for (int j = 0; j < 8; ++j) {
                vfloat4 o = v[j] * sig;
                __builtin_nontemporal_store(o, po + (size_t)(c0 + 7 - j) * S4);
            }
        }
    }
}

extern "C" void kernel_launch(void* const* d_in, const int* in_sizes, int n_in,
                              void* d_out, int out_size, void* d_ws, size_t ws_size,
                              hipStream_t stream) {
    const float* x  = (const float*)d_in[0];
    const float* cw = (const float*)d_in[1];
    float* out = (float*)d_out;

    sa_onepass<<<BB * (HH / RPB), 256, 0, stream>>>(x, cw, out);  // 512 blocks
}